// Round 5
// baseline (98.734 us; speedup 1.0000x reference)
//
#include <hip/hip_runtime.h>
#include <math.h>

#define NMOD 4
#define BB   8
#define NN   4096
#define MM   4608
#define TPB  256

// ---- fast path geometry ----
#define QPT      8                      // queries per thread (named scalars/pairs)
#define QPB      (TPB * QPT)            // 2048 queries per block
#define NXB      (NN / QPB)             // 2
#define SLICES   24
#define SLICE_M  (MM / SLICES)          // 192
#define QCOUNT   (NMOD * BB * NN)       // 131072
#define KEYB     ((size_t)QCOUNT * 8)   // 1 MiB packed keys
#define NXBLK2   (NN / TPB)             // 16
#define NPART    (NMOD * BB * NXBLK2)   // 512
#define WS_NEED  (KEYB + NPART * sizeof(float))

typedef float v2f __attribute__((ext_vector_type(2)));

static __device__ __forceinline__ v2f pkfma(v2f a, v2f b, v2f c) {
    v2f d;
    asm("v_pk_fma_f32 %0, %1, %2, %3" : "=v"(d) : "v"(a), "v"(b), "v"(c));
    return d;
}

// ---------------- pass 1: query-paired pk_fma slice argmin ------------------
__global__ __launch_bounds__(TPB, 6) void nn_min_kernel(
    const float* __restrict__ noisy, const float* __restrict__ clean,
    const float* __restrict__ seeds, const float* __restrict__ stds,
    const float* __restrict__ disp,  const float* __restrict__ noise,
    unsigned long long* __restrict__ keys)
{
    __shared__ float4 TA[SLICE_M];   // (x,x,y,y) per target
    __shared__ float4 TB[SLICE_M];   // (z,z,w,w) per target, w = ||t||^2

    const int tid   = threadIdx.x;
    const int b     = blockIdx.y;
    const int mod   = blockIdx.z / SLICES;
    const int sl    = blockIdx.z % SLICES;
    const int mbase = sl * SLICE_M;
    const int nb    = blockIdx.x * QPB + tid;

    const float sx = seeds[b * 3 + 0];
    const float sy = seeds[b * 3 + 1];
    const float sz = seeds[b * 3 + 2];
    float nstd = 0.0f;
    if (mod == 0) nstd = stds[b] * 0.25f;
    else if (mod == 1) nstd = stds[b] * 0.0625f;
    const bool nt = (mod < 2);

    // stage this 192-target slice, duplicated for pk broadcast
    if (tid < SLICE_M) {
        const int m = mbase + tid;
        const size_t oc = ((size_t)b * MM + m) * 3;
        float tx = clean[oc + 0] - sx;
        float ty = clean[oc + 1] - sy;
        float tz = clean[oc + 2] - sz;
        if (nt) {
            const size_t on = (((size_t)mod * BB + b) * MM + m) * 3;
            tx = fmaf(noise[on + 0], nstd, tx);
            ty = fmaf(noise[on + 1], nstd, ty);
            tz = fmaf(noise[on + 2], nstd, tz);
        }
        const float tw = fmaf(tx, tx, fmaf(ty, ty, tz * tz));
        TA[tid] = make_float4(tx, tx, ty, ty);
        TB[tid] = make_float4(tz, tz, tw, tw);
    }

    // ---- 8 queries as named scalars, then packed into 4 query-pairs ----
    float m2x0, m2y0, m2z0, m2x1, m2y1, m2z1, m2x2, m2y2, m2z2, m2x3, m2y3, m2z3;
    float m2x4, m2y4, m2z4, m2x5, m2y5, m2z5, m2x6, m2y6, m2z6, m2x7, m2y7, m2z7;

#define QSETUP(K, MX, MY, MZ) do {                                        \
        const int n = nb + (K) * TPB;                                     \
        const size_t o0 = ((size_t)b * NN + n) * 3;                       \
        float qx = noisy[o0 + 0] - sx;                                    \
        float qy = noisy[o0 + 1] - sy;                                    \
        float qz = noisy[o0 + 2] - sz;                                    \
        for (int j = 0; j < mod; ++j) {                                   \
            const size_t o = (((size_t)j * BB + b) * NN + n) * 3;         \
            qx += disp[o + 0]; qy += disp[o + 1]; qz += disp[o + 2];      \
        }                                                                 \
        MX = -2.0f * qx; MY = -2.0f * qy; MZ = -2.0f * qz;                \
    } while (0)

    QSETUP(0, m2x0, m2y0, m2z0); QSETUP(1, m2x1, m2y1, m2z1);
    QSETUP(2, m2x2, m2y2, m2z2); QSETUP(3, m2x3, m2y3, m2z3);
    QSETUP(4, m2x4, m2y4, m2z4); QSETUP(5, m2x5, m2y5, m2z5);
    QSETUP(6, m2x6, m2y6, m2z6); QSETUP(7, m2x7, m2y7, m2z7);
#undef QSETUP

    const v2f Qx0 = {m2x0, m2x1}, Qy0 = {m2y0, m2y1}, Qz0 = {m2z0, m2z1};
    const v2f Qx1 = {m2x2, m2x3}, Qy1 = {m2y2, m2y3}, Qz1 = {m2z2, m2z3};
    const v2f Qx2 = {m2x4, m2x5}, Qy2 = {m2y4, m2y5}, Qz2 = {m2z4, m2z5};
    const v2f Qx3 = {m2x6, m2x7}, Qy3 = {m2y6, m2y7}, Qz3 = {m2z6, m2z7};

    __syncthreads();

    float b0 = INFINITY, b1 = INFINITY, b2 = INFINITY, b3 = INFINITY;
    float b4 = INFINITY, b5 = INFINITY, b6 = INFINITY, b7 = INFINITY;
    int i0 = 0, i1 = 0, i2 = 0, i3 = 0, i4 = 0, i5 = 0, i6 = 0, i7 = 0;

#define UPD(D, Bv, Iv, Mi) do {                                           \
        const bool c = (D) < (Bv);                                        \
        Bv = c ? (D) : (Bv);                                              \
        Iv = c ? (Mi) : (Iv);                                             \
    } while (0)

    #pragma unroll 4
    for (int m = 0; m < SLICE_M; ++m) {
        const float4 A  = TA[m];   // (x,x,y,y)
        const float4 Bq = TB[m];   // (z,z,w,w)
        const v2f xs = {A.x,  A.y};
        const v2f ys = {A.z,  A.w};
        const v2f zs = {Bq.x, Bq.y};
        const v2f ws = {Bq.z, Bq.w};

        v2f a0 = pkfma(Qz0, zs, ws); a0 = pkfma(Qy0, ys, a0); a0 = pkfma(Qx0, xs, a0);
        v2f a1 = pkfma(Qz1, zs, ws); a1 = pkfma(Qy1, ys, a1); a1 = pkfma(Qx1, xs, a1);
        v2f a2 = pkfma(Qz2, zs, ws); a2 = pkfma(Qy2, ys, a2); a2 = pkfma(Qx2, xs, a2);
        v2f a3 = pkfma(Qz3, zs, ws); a3 = pkfma(Qy3, ys, a3); a3 = pkfma(Qx3, xs, a3);

        UPD(a0.x, b0, i0, m); UPD(a0.y, b1, i1, m);
        UPD(a1.x, b2, i2, m); UPD(a1.y, b3, i3, m);
        UPD(a2.x, b4, i4, m); UPD(a2.y, b5, i5, m);
        UPD(a3.x, b6, i6, m); UPD(a3.y, b7, i7, m);
    }
#undef UPD

    const size_t qbase = (((size_t)mod * BB + b) * NN);

#define FINISH(K, MXE, MYE, MZE, Bv, Iv) do {                             \
        const float q2 = 0.25f * fmaf(MXE, MXE,                           \
                             fmaf(MYE, MYE, (MZE) * (MZE)));              \
        const float f = (Bv) + q2 + 8.0f;                                 \
        const unsigned long long key =                                    \
            ((unsigned long long)__float_as_uint(f) << 32) |              \
            (unsigned int)(mbase + (Iv));                                 \
        atomicMin(&keys[qbase + (size_t)(nb + (K) * TPB)], key);          \
    } while (0)

    FINISH(0, Qx0.x, Qy0.x, Qz0.x, b0, i0);
    FINISH(1, Qx0.y, Qy0.y, Qz0.y, b1, i1);
    FINISH(2, Qx1.x, Qy1.x, Qz1.x, b2, i2);
    FINISH(3, Qx1.y, Qy1.y, Qz1.y, b3, i3);
    FINISH(4, Qx2.x, Qy2.x, Qz2.x, b4, i4);
    FINISH(5, Qx2.y, Qy2.y, Qz2.y, b5, i5);
    FINISH(6, Qx3.x, Qy3.x, Qz3.x, b6, i6);
    FINISH(7, Qx3.y, Qy3.y, Qz3.y, b7, i7);
#undef FINISH
}

// ---------------- pass 2: unpack winner, compute loss terms -----------------
__global__ __launch_bounds__(TPB) void nn_loss_pass2(
    const float* __restrict__ noisy, const float* __restrict__ clean,
    const float* __restrict__ seeds, const float* __restrict__ stds,
    const float* __restrict__ disp,  const float* __restrict__ noise,
    const unsigned long long* __restrict__ keys,
    float* __restrict__ partials)
{
    __shared__ float red[TPB / 64];
    const int tid = threadIdx.x;
    const int b   = blockIdx.y;
    const int mod = blockIdx.z;
    const int n   = blockIdx.x * TPB + tid;

    const float sx = seeds[b * 3 + 0];
    const float sy = seeds[b * 3 + 1];
    const float sz = seeds[b * 3 + 2];
    float nstd = 0.0f;
    if (mod == 0) nstd = stds[b] * 0.25f;
    else if (mod == 1) nstd = stds[b] * 0.0625f;

    float qx = noisy[((size_t)b * NN + n) * 3 + 0] - sx;
    float qy = noisy[((size_t)b * NN + n) * 3 + 1] - sy;
    float qz = noisy[((size_t)b * NN + n) * 3 + 2] - sz;
    for (int j = 0; j < mod; ++j) {
        const size_t o = (((size_t)j * BB + b) * NN + n) * 3;
        qx += disp[o + 0]; qy += disp[o + 1]; qz += disp[o + 2];
    }
    const size_t od = (((size_t)mod * BB + b) * NN + n) * 3;
    const float dxp = disp[od + 0];
    const float dyp = disp[od + 1];
    const float dzp = disp[od + 2];

    const unsigned gidx =
        (unsigned)(keys[(((size_t)mod * BB + b) * NN) + n] & 0xFFFFFFFFull);

    const size_t oc = ((size_t)b * MM + gidx) * 3;
    float tx = clean[oc + 0] - sx;
    float ty = clean[oc + 1] - sy;
    float tz = clean[oc + 2] - sz;
    if (mod < 2) {
        const size_t on = (((size_t)mod * BB + b) * MM + gidx) * 3;
        tx = fmaf(noise[on + 0], nstd, tx);
        ty = fmaf(noise[on + 1], nstd, ty);
        tz = fmaf(noise[on + 2], nstd, tz);
    }
    const float ex = dxp - (tx - qx);
    const float ey = dyp - (ty - qy);
    const float ez = dzp - (tz - qz);
    float v = fmaf(ex, ex, fmaf(ey, ey, ez * ez));

    for (int o = 32; o; o >>= 1) v += __shfl_down(v, o);
    if ((tid & 63) == 0) red[tid >> 6] = v;
    __syncthreads();
    if (tid == 0) {
        const float s = red[0] + red[1] + red[2] + red[3];
        partials[(((size_t)mod * BB + b) * NXBLK2) + blockIdx.x] = s;
    }
}

__global__ void finalize_kernel(const float* __restrict__ partials, float* __restrict__ out) {
    float s = 0.0f;
    for (int k = threadIdx.x; k < NPART; k += 64) s += partials[k];
    for (int o = 32; o; o >>= 1) s += __shfl_down(s, o);
    if (threadIdx.x == 0) {
        out[0] = s * (1.0f / BB);
        out[1] = s * (1.0f / BB);
    }
}

// ---------------- monolithic fallback (needs only 2 KiB ws) -----------------
#define TM 768
__global__ __launch_bounds__(TPB) void nn_loss_kernel(
    const float* __restrict__ noisy, const float* __restrict__ clean,
    const float* __restrict__ seeds, const float* __restrict__ stds,
    const float* __restrict__ disp,  const float* __restrict__ noise,
    float* __restrict__ partials)
{
    __shared__ float4 tgt[TM];
    __shared__ float red[TPB / 64];
    const int tid = threadIdx.x;
    const int b = blockIdx.y, mod = blockIdx.z;
    const int n = blockIdx.x * TPB + tid;
    const float sx = seeds[b*3+0], sy = seeds[b*3+1], sz = seeds[b*3+2];
    float qx = noisy[((size_t)b*NN+n)*3+0] - sx;
    float qy = noisy[((size_t)b*NN+n)*3+1] - sy;
    float qz = noisy[((size_t)b*NN+n)*3+2] - sz;
    for (int j = 0; j < mod; ++j) {
        const size_t o = (((size_t)j*BB + b)*NN + n)*3;
        qx += disp[o+0]; qy += disp[o+1]; qz += disp[o+2];
    }
    const size_t od = (((size_t)mod*BB + b)*NN + n)*3;
    const float dxp = disp[od+0], dyp = disp[od+1], dzp = disp[od+2];
    float nstd = 0.0f;
    if (mod == 0) nstd = stds[b]*0.25f; else if (mod == 1) nstd = stds[b]*0.0625f;
    const bool nt = (mod < 2);
    const float m2x = -2.0f*qx, m2y = -2.0f*qy, m2z = -2.0f*qz;
    float best = INFINITY; int bestm = 0;
    for (int mt = 0; mt < MM; mt += TM) {
        __syncthreads();
        for (int k = tid; k < TM; k += TPB) {
            const int m = mt + k;
            const size_t oc = ((size_t)b*MM + m)*3;
            float tx = clean[oc+0]-sx, ty = clean[oc+1]-sy, tz = clean[oc+2]-sz;
            if (nt) {
                const size_t on = (((size_t)mod*BB + b)*MM + m)*3;
                tx = fmaf(noise[on+0], nstd, tx);
                ty = fmaf(noise[on+1], nstd, ty);
                tz = fmaf(noise[on+2], nstd, tz);
            }
            tgt[k] = make_float4(tx, ty, tz, fmaf(tx,tx,fmaf(ty,ty,tz*tz)));
        }
        __syncthreads();
        #pragma unroll 8
        for (int k = 0; k < TM; ++k) {
            const float4 t = tgt[k];
            const float d2 = fmaf(m2x, t.x, fmaf(m2y, t.y, fmaf(m2z, t.z, t.w)));
            if (d2 < best) { best = d2; bestm = mt + k; }
        }
    }
    const size_t oc = ((size_t)b*MM + bestm)*3;
    float tx = clean[oc+0]-sx, ty = clean[oc+1]-sy, tz = clean[oc+2]-sz;
    if (nt) {
        const size_t on = (((size_t)mod*BB + b)*MM + bestm)*3;
        tx = fmaf(noise[on+0], nstd, tx);
        ty = fmaf(noise[on+1], nstd, ty);
        tz = fmaf(noise[on+2], nstd, tz);
    }
    const float ex = dxp - (tx - qx), ey = dyp - (ty - qy), ez = dzp - (tz - qz);
    float v = fmaf(ex, ex, fmaf(ey, ey, ez*ez));
    for (int o = 32; o; o >>= 1) v += __shfl_down(v, o);
    if ((tid & 63) == 0) red[tid >> 6] = v;
    __syncthreads();
    if (tid == 0)
        partials[(((size_t)mod*BB + b)*NXBLK2) + blockIdx.x] = red[0]+red[1]+red[2]+red[3];
}

extern "C" void kernel_launch(void* const* d_in, const int* in_sizes, int n_in,
                              void* d_out, int out_size, void* d_ws, size_t ws_size,
                              hipStream_t stream) {
    const float* noisy = (const float*)d_in[0];
    const float* clean = (const float*)d_in[1];
    const float* seeds = (const float*)d_in[2];
    const float* stds  = (const float*)d_in[3];
    const float* disp  = (const float*)d_in[4];
    const float* noise = (const float*)d_in[5];
    float* out = (float*)d_out;

    if (ws_size >= WS_NEED) {
        unsigned long long* keys = (unsigned long long*)d_ws;
        float* partials = (float*)((char*)d_ws + KEYB);
        hipMemsetAsync(d_ws, 0xFF, KEYB, stream);
        dim3 g1(NXB, BB, NMOD * SLICES);
        nn_min_kernel<<<g1, TPB, 0, stream>>>(noisy, clean, seeds, stds, disp, noise, keys);
        dim3 g2(NXBLK2, BB, NMOD);
        nn_loss_pass2<<<g2, TPB, 0, stream>>>(noisy, clean, seeds, stds, disp, noise, keys, partials);
        finalize_kernel<<<1, 64, 0, stream>>>(partials, out);
    } else {
        float* partials = (float*)d_ws;
        dim3 grid(NXBLK2, BB, NMOD);
        nn_loss_kernel<<<grid, TPB, 0, stream>>>(noisy, clean, seeds, stds, disp, noise, partials);
        finalize_kernel<<<1, 64, 0, stream>>>(partials, out);
    }
}

// Round 6
// 85.682 us; speedup vs baseline: 1.1523x; 1.1523x over previous
//
#include <hip/hip_runtime.h>
#include <math.h>

#define NMOD 4
#define BB   8
#define NN   4096
#define MM   4608
#define TPB  256

// ---- fast path geometry ----
#define QPT      8                      // queries per thread (named scalars)
#define QPB      (TPB * QPT)            // 2048 queries per block
#define NXB      (NN / QPB)             // 2
#define SLICES   16
#define SLICE_M  (MM / SLICES)          // 288
#define CH       16                     // chunk size for argmin bookkeeping
#define NCHUNK   (SLICE_M / CH)         // 18
#define QCOUNT   (NMOD * BB * NN)       // 131072
#define KEYB     ((size_t)QCOUNT * 8)   // 1 MiB packed keys
#define NXBLK2   (NN / TPB)             // 16
#define NPART    (NMOD * BB * NXBLK2)   // 512
#define WS_NEED  (KEYB + NPART * sizeof(float))

static __device__ __forceinline__ float min3f(float a, float b, float c) {
    float d;
    asm("v_min3_f32 %0, %1, %2, %3" : "=v"(d) : "v"(a), "v"(b), "v"(c));
    return d;
}

// identical FMA chain used in scan and rescan -> bit-exact equality
#define CHAIN(T, MX, MY, MZ) \
    fmaf(MX, (T).x, fmaf(MY, (T).y, fmaf(MZ, (T).z, (T).w)))

// ---------------- pass 1: chunked min3 slice argmin -------------------------
__global__ __launch_bounds__(TPB, 4) void nn_min_kernel(
    const float* __restrict__ noisy, const float* __restrict__ clean,
    const float* __restrict__ seeds, const float* __restrict__ stds,
    const float* __restrict__ disp,  const float* __restrict__ noise,
    unsigned long long* __restrict__ keys)
{
    __shared__ float4 TS[SLICE_M];   // {x,y,z,||t||^2}

    const int tid   = threadIdx.x;
    const int b     = blockIdx.y;
    const int mod   = blockIdx.z >> 4;
    const int sl    = blockIdx.z & 15;
    const int mbase = sl * SLICE_M;
    const int nb    = blockIdx.x * QPB + tid;

    const float sx = seeds[b * 3 + 0];
    const float sy = seeds[b * 3 + 1];
    const float sz = seeds[b * 3 + 2];
    float nstd = 0.0f;
    if (mod == 0) nstd = stds[b] * 0.25f;
    else if (mod == 1) nstd = stds[b] * 0.0625f;
    const bool nt = (mod < 2);

    // stage this 288-target slice
    for (int k = tid; k < SLICE_M; k += TPB) {
        const int m = mbase + k;
        const size_t oc = ((size_t)b * MM + m) * 3;
        float tx = clean[oc + 0] - sx;
        float ty = clean[oc + 1] - sy;
        float tz = clean[oc + 2] - sz;
        if (nt) {
            const size_t on = (((size_t)mod * BB + b) * MM + m) * 3;
            tx = fmaf(noise[on + 0], nstd, tx);
            ty = fmaf(noise[on + 1], nstd, ty);
            tz = fmaf(noise[on + 2], nstd, tz);
        }
        const float tw = fmaf(tx, tx, fmaf(ty, ty, tz * tz));
        TS[k] = make_float4(tx, ty, tz, tw);
    }

    // ---- 8 queries, all named scalars (no arrays -> no scratch) ----
    float m2x0, m2y0, m2z0, m2x1, m2y1, m2z1, m2x2, m2y2, m2z2, m2x3, m2y3, m2z3;
    float m2x4, m2y4, m2z4, m2x5, m2y5, m2z5, m2x6, m2y6, m2z6, m2x7, m2y7, m2z7;

#define QSETUP(K, MX, MY, MZ) do {                                        \
        const int n = nb + (K) * TPB;                                     \
        const size_t o0 = ((size_t)b * NN + n) * 3;                       \
        float qx = noisy[o0 + 0] - sx;                                    \
        float qy = noisy[o0 + 1] - sy;                                    \
        float qz = noisy[o0 + 2] - sz;                                    \
        for (int j = 0; j < mod; ++j) {                                   \
            const size_t o = (((size_t)j * BB + b) * NN + n) * 3;         \
            qx += disp[o + 0]; qy += disp[o + 1]; qz += disp[o + 2];      \
        }                                                                 \
        MX = -2.0f * qx; MY = -2.0f * qy; MZ = -2.0f * qz;                \
    } while (0)

    QSETUP(0, m2x0, m2y0, m2z0); QSETUP(1, m2x1, m2y1, m2z1);
    QSETUP(2, m2x2, m2y2, m2z2); QSETUP(3, m2x3, m2y3, m2z3);
    QSETUP(4, m2x4, m2y4, m2z4); QSETUP(5, m2x5, m2y5, m2z5);
    QSETUP(6, m2x6, m2y6, m2z6); QSETUP(7, m2x7, m2y7, m2z7);
#undef QSETUP

    __syncthreads();

    float bb0 = INFINITY, bb1 = INFINITY, bb2 = INFINITY, bb3 = INFINITY;
    float bb4 = INFINITY, bb5 = INFINITY, bb6 = INFINITY, bb7 = INFINITY;
    int cc0 = 0, cc1 = 0, cc2 = 0, cc3 = 0, cc4 = 0, cc5 = 0, cc6 = 0, cc7 = 0;

    for (int c = 0; c < NCHUNK; ++c) {
        const int base = c * CH;
        float a0 = INFINITY, a1 = INFINITY, a2 = INFINITY, a3 = INFINITY;
        float a4 = INFINITY, a5 = INFINITY, a6 = INFINITY, a7 = INFINITY;

        #pragma unroll
        for (int u = 0; u < CH; u += 2) {
            const float4 t0 = TS[base + u];
            const float4 t1 = TS[base + u + 1];
#define EVAL2(MX, MY, MZ, A) do {                                         \
            const float d0 = CHAIN(t0, MX, MY, MZ);                       \
            const float d1 = CHAIN(t1, MX, MY, MZ);                       \
            A = min3f(d0, d1, A);                                         \
        } while (0)
            EVAL2(m2x0, m2y0, m2z0, a0);
            EVAL2(m2x1, m2y1, m2z1, a1);
            EVAL2(m2x2, m2y2, m2z2, a2);
            EVAL2(m2x3, m2y3, m2z3, a3);
            EVAL2(m2x4, m2y4, m2z4, a4);
            EVAL2(m2x5, m2y5, m2z5, a5);
            EVAL2(m2x6, m2y6, m2z6, a6);
            EVAL2(m2x7, m2y7, m2z7, a7);
#undef EVAL2
        }

#define CUPD(A, BV, CV) do {                                              \
        const bool c_ = (A) < (BV);                                       \
        BV = c_ ? (A) : (BV);                                             \
        CV = c_ ? c : (CV);                                               \
    } while (0)
        CUPD(a0, bb0, cc0); CUPD(a1, bb1, cc1);
        CUPD(a2, bb2, cc2); CUPD(a3, bb3, cc3);
        CUPD(a4, bb4, cc4); CUPD(a5, bb5, cc5);
        CUPD(a6, bb6, cc6); CUPD(a7, bb7, cc7);
#undef CUPD
    }

    const size_t qbase = (((size_t)mod * BB + b) * NN);

    // rescan winning chunk (backward overwrite -> first match), pack, combine
#define FINQ(K, MX, MY, MZ, BV, CV) do {                                  \
        int im = 0;                                                       \
        const int rb = (CV) * CH;                                         \
        for (int u = CH - 1; u >= 0; --u) {                               \
            const float4 t = TS[rb + u];                                  \
            const float d = CHAIN(t, MX, MY, MZ);                         \
            im = (d == (BV)) ? (rb + u) : im;                             \
        }                                                                 \
        const float q2 = 0.25f * fmaf(MX, MX, fmaf(MY, MY, (MZ) * (MZ)));\
        const float f = (BV) + q2 + 8.0f;                                 \
        const unsigned long long key =                                    \
            ((unsigned long long)__float_as_uint(f) << 32) |              \
            (unsigned int)(mbase + im);                                   \
        atomicMin(&keys[qbase + (size_t)(nb + (K) * TPB)], key);          \
    } while (0)

    FINQ(0, m2x0, m2y0, m2z0, bb0, cc0);
    FINQ(1, m2x1, m2y1, m2z1, bb1, cc1);
    FINQ(2, m2x2, m2y2, m2z2, bb2, cc2);
    FINQ(3, m2x3, m2y3, m2z3, bb3, cc3);
    FINQ(4, m2x4, m2y4, m2z4, bb4, cc4);
    FINQ(5, m2x5, m2y5, m2z5, bb5, cc5);
    FINQ(6, m2x6, m2y6, m2z6, bb6, cc6);
    FINQ(7, m2x7, m2y7, m2z7, bb7, cc7);
#undef FINQ
}

// ---------------- pass 2: unpack winner, compute loss terms -----------------
__global__ __launch_bounds__(TPB) void nn_loss_pass2(
    const float* __restrict__ noisy, const float* __restrict__ clean,
    const float* __restrict__ seeds, const float* __restrict__ stds,
    const float* __restrict__ disp,  const float* __restrict__ noise,
    const unsigned long long* __restrict__ keys,
    float* __restrict__ partials)
{
    __shared__ float red[TPB / 64];
    const int tid = threadIdx.x;
    const int b   = blockIdx.y;
    const int mod = blockIdx.z;
    const int n   = blockIdx.x * TPB + tid;

    const float sx = seeds[b * 3 + 0];
    const float sy = seeds[b * 3 + 1];
    const float sz = seeds[b * 3 + 2];
    float nstd = 0.0f;
    if (mod == 0) nstd = stds[b] * 0.25f;
    else if (mod == 1) nstd = stds[b] * 0.0625f;

    float qx = noisy[((size_t)b * NN + n) * 3 + 0] - sx;
    float qy = noisy[((size_t)b * NN + n) * 3 + 1] - sy;
    float qz = noisy[((size_t)b * NN + n) * 3 + 2] - sz;
    for (int j = 0; j < mod; ++j) {
        const size_t o = (((size_t)j * BB + b) * NN + n) * 3;
        qx += disp[o + 0]; qy += disp[o + 1]; qz += disp[o + 2];
    }
    const size_t od = (((size_t)mod * BB + b) * NN + n) * 3;
    const float dxp = disp[od + 0];
    const float dyp = disp[od + 1];
    const float dzp = disp[od + 2];

    const unsigned gidx =
        (unsigned)(keys[(((size_t)mod * BB + b) * NN) + n] & 0xFFFFFFFFull);

    const size_t oc = ((size_t)b * MM + gidx) * 3;
    float tx = clean[oc + 0] - sx;
    float ty = clean[oc + 1] - sy;
    float tz = clean[oc + 2] - sz;
    if (mod < 2) {
        const size_t on = (((size_t)mod * BB + b) * MM + gidx) * 3;
        tx = fmaf(noise[on + 0], nstd, tx);
        ty = fmaf(noise[on + 1], nstd, ty);
        tz = fmaf(noise[on + 2], nstd, tz);
    }
    const float ex = dxp - (tx - qx);
    const float ey = dyp - (ty - qy);
    const float ez = dzp - (tz - qz);
    float v = fmaf(ex, ex, fmaf(ey, ey, ez * ez));

    for (int o = 32; o; o >>= 1) v += __shfl_down(v, o);
    if ((tid & 63) == 0) red[tid >> 6] = v;
    __syncthreads();
    if (tid == 0) {
        const float s = red[0] + red[1] + red[2] + red[3];
        partials[(((size_t)mod * BB + b) * NXBLK2) + blockIdx.x] = s;
    }
}

__global__ void finalize_kernel(const float* __restrict__ partials, float* __restrict__ out) {
    float s = 0.0f;
    for (int k = threadIdx.x; k < NPART; k += 64) s += partials[k];
    for (int o = 32; o; o >>= 1) s += __shfl_down(s, o);
    if (threadIdx.x == 0) {
        out[0] = s * (1.0f / BB);
        out[1] = s * (1.0f / BB);
    }
}

// ---------------- monolithic fallback (needs only 2 KiB ws) -----------------
#define TM 768
__global__ __launch_bounds__(TPB) void nn_loss_kernel(
    const float* __restrict__ noisy, const float* __restrict__ clean,
    const float* __restrict__ seeds, const float* __restrict__ stds,
    const float* __restrict__ disp,  const float* __restrict__ noise,
    float* __restrict__ partials)
{
    __shared__ float4 tgt[TM];
    __shared__ float red[TPB / 64];
    const int tid = threadIdx.x;
    const int b = blockIdx.y, mod = blockIdx.z;
    const int n = blockIdx.x * TPB + tid;
    const float sx = seeds[b*3+0], sy = seeds[b*3+1], sz = seeds[b*3+2];
    float qx = noisy[((size_t)b*NN+n)*3+0] - sx;
    float qy = noisy[((size_t)b*NN+n)*3+1] - sy;
    float qz = noisy[((size_t)b*NN+n)*3+2] - sz;
    for (int j = 0; j < mod; ++j) {
        const size_t o = (((size_t)j*BB + b)*NN + n)*3;
        qx += disp[o+0]; qy += disp[o+1]; qz += disp[o+2];
    }
    const size_t od = (((size_t)mod*BB + b)*NN + n)*3;
    const float dxp = disp[od+0], dyp = disp[od+1], dzp = disp[od+2];
    float nstd = 0.0f;
    if (mod == 0) nstd = stds[b]*0.25f; else if (mod == 1) nstd = stds[b]*0.0625f;
    const bool nt = (mod < 2);
    const float m2x = -2.0f*qx, m2y = -2.0f*qy, m2z = -2.0f*qz;
    float best = INFINITY; int bestm = 0;
    for (int mt = 0; mt < MM; mt += TM) {
        __syncthreads();
        for (int k = tid; k < TM; k += TPB) {
            const int m = mt + k;
            const size_t oc = ((size_t)b*MM + m)*3;
            float tx = clean[oc+0]-sx, ty = clean[oc+1]-sy, tz = clean[oc+2]-sz;
            if (nt) {
                const size_t on = (((size_t)mod*BB + b)*MM + m)*3;
                tx = fmaf(noise[on+0], nstd, tx);
                ty = fmaf(noise[on+1], nstd, ty);
                tz = fmaf(noise[on+2], nstd, tz);
            }
            tgt[k] = make_float4(tx, ty, tz, fmaf(tx,tx,fmaf(ty,ty,tz*tz)));
        }
        __syncthreads();
        #pragma unroll 8
        for (int k = 0; k < TM; ++k) {
            const float4 t = tgt[k];
            const float d2 = fmaf(m2x, t.x, fmaf(m2y, t.y, fmaf(m2z, t.z, t.w)));
            if (d2 < best) { best = d2; bestm = mt + k; }
        }
    }
    const size_t oc = ((size_t)b*MM + bestm)*3;
    float tx = clean[oc+0]-sx, ty = clean[oc+1]-sy, tz = clean[oc+2]-sz;
    if (nt) {
        const size_t on = (((size_t)mod*BB + b)*MM + bestm)*3;
        tx = fmaf(noise[on+0], nstd, tx);
        ty = fmaf(noise[on+1], nstd, ty);
        tz = fmaf(noise[on+2], nstd, tz);
    }
    const float ex = dxp - (tx - qx), ey = dyp - (ty - qy), ez = dzp - (tz - qz);
    float v = fmaf(ex, ex, fmaf(ey, ey, ez*ez));
    for (int o = 32; o; o >>= 1) v += __shfl_down(v, o);
    if ((tid & 63) == 0) red[tid >> 6] = v;
    __syncthreads();
    if (tid == 0)
        partials[(((size_t)mod*BB + b)*NXBLK2) + blockIdx.x] = red[0]+red[1]+red[2]+red[3];
}

extern "C" void kernel_launch(void* const* d_in, const int* in_sizes, int n_in,
                              void* d_out, int out_size, void* d_ws, size_t ws_size,
                              hipStream_t stream) {
    const float* noisy = (const float*)d_in[0];
    const float* clean = (const float*)d_in[1];
    const float* seeds = (const float*)d_in[2];
    const float* stds  = (const float*)d_in[3];
    const float* disp  = (const float*)d_in[4];
    const float* noise = (const float*)d_in[5];
    float* out = (float*)d_out;

    if (ws_size >= WS_NEED) {
        unsigned long long* keys = (unsigned long long*)d_ws;
        float* partials = (float*)((char*)d_ws + KEYB);
        hipMemsetAsync(d_ws, 0xFF, KEYB, stream);
        dim3 g1(NXB, BB, NMOD * SLICES);
        nn_min_kernel<<<g1, TPB, 0, stream>>>(noisy, clean, seeds, stds, disp, noise, keys);
        dim3 g2(NXBLK2, BB, NMOD);
        nn_loss_pass2<<<g2, TPB, 0, stream>>>(noisy, clean, seeds, stds, disp, noise, keys, partials);
        finalize_kernel<<<1, 64, 0, stream>>>(partials, out);
    } else {
        float* partials = (float*)d_ws;
        dim3 grid(NXBLK2, BB, NMOD);
        nn_loss_kernel<<<grid, TPB, 0, stream>>>(noisy, clean, seeds, stds, disp, noise, partials);
        finalize_kernel<<<1, 64, 0, stream>>>(partials, out);
    }
}

// Round 7
// 83.938 us; speedup vs baseline: 1.1763x; 1.0208x over previous
//
#include <hip/hip_runtime.h>
#include <math.h>

#define NMOD 4
#define BB   8
#define NN   4096
#define MM   4608
#define TPB  256

// ---- fast path geometry ----
#define QPT      8                      // queries per thread (named scalars)
#define QPB      (TPB * QPT)            // 2048 queries per block
#define NXB      (NN / QPB)             // 2
#define SLICES   32
#define SLICE_M  (MM / SLICES)          // 144
#define CH       16                     // chunk size for argmin bookkeeping
#define NCHUNK   (SLICE_M / CH)         // 9
#define CHP      (CH + 1)               // padded chunk stride (breaks bank aliasing)
#define QCOUNT   (NMOD * BB * NN)       // 131072
#define KEYB     ((size_t)QCOUNT * 8)   // 1 MiB packed keys
#define NXBLK2   (NN / TPB)             // 16
#define NPART    (NMOD * BB * NXBLK2)   // 512
#define WS_NEED  (KEYB + NPART * sizeof(float))

static __device__ __forceinline__ float min3f(float a, float b, float c) {
    float d;
    asm("v_min3_f32 %0, %1, %2, %3" : "=v"(d) : "v"(a), "v"(b), "v"(c));
    return d;
}

// identical FMA chain used in scan and rescan -> bit-exact equality
#define CHAIN(T, MX, MY, MZ) \
    fmaf(MX, (T).x, fmaf(MY, (T).y, fmaf(MZ, (T).z, (T).w)))

// ---------------- pass 1: chunked min3 slice argmin -------------------------
__global__ __launch_bounds__(TPB, 8) void nn_min_kernel(
    const float* __restrict__ noisy, const float* __restrict__ clean,
    const float* __restrict__ seeds, const float* __restrict__ stds,
    const float* __restrict__ disp,  const float* __restrict__ noise,
    unsigned long long* __restrict__ keys)
{
    __shared__ float4 TS[NCHUNK][CHP];   // {x,y,z,||t||^2}, +1 pad per chunk

    const int tid   = threadIdx.x;
    const int b     = blockIdx.y;
    const int mod   = blockIdx.z >> 5;
    const int sl    = blockIdx.z & 31;
    const int mbase = sl * SLICE_M;
    const int nb    = blockIdx.x * QPB + tid;

    const float sx = seeds[b * 3 + 0];
    const float sy = seeds[b * 3 + 1];
    const float sz = seeds[b * 3 + 2];
    float nstd = 0.0f;
    if (mod == 0) nstd = stds[b] * 0.25f;
    else if (mod == 1) nstd = stds[b] * 0.0625f;
    const bool nt = (mod < 2);

    // stage this 144-target slice (one pass, tid<144)
    if (tid < SLICE_M) {
        const int m = mbase + tid;
        const size_t oc = ((size_t)b * MM + m) * 3;
        float tx = clean[oc + 0] - sx;
        float ty = clean[oc + 1] - sy;
        float tz = clean[oc + 2] - sz;
        if (nt) {
            const size_t on = (((size_t)mod * BB + b) * MM + m) * 3;
            tx = fmaf(noise[on + 0], nstd, tx);
            ty = fmaf(noise[on + 1], nstd, ty);
            tz = fmaf(noise[on + 2], nstd, tz);
        }
        const float tw = fmaf(tx, tx, fmaf(ty, ty, tz * tz));
        TS[tid >> 4][tid & 15] = make_float4(tx, ty, tz, tw);
    }

    // ---- 8 queries, all named scalars (no arrays -> no scratch) ----
    float m2x0, m2y0, m2z0, m2x1, m2y1, m2z1, m2x2, m2y2, m2z2, m2x3, m2y3, m2z3;
    float m2x4, m2y4, m2z4, m2x5, m2y5, m2z5, m2x6, m2y6, m2z6, m2x7, m2y7, m2z7;

#define QSETUP(K, MX, MY, MZ) do {                                        \
        const int n = nb + (K) * TPB;                                     \
        const size_t o0 = ((size_t)b * NN + n) * 3;                       \
        float qx = noisy[o0 + 0] - sx;                                    \
        float qy = noisy[o0 + 1] - sy;                                    \
        float qz = noisy[o0 + 2] - sz;                                    \
        for (int j = 0; j < mod; ++j) {                                   \
            const size_t o = (((size_t)j * BB + b) * NN + n) * 3;         \
            qx += disp[o + 0]; qy += disp[o + 1]; qz += disp[o + 2];      \
        }                                                                 \
        MX = -2.0f * qx; MY = -2.0f * qy; MZ = -2.0f * qz;                \
    } while (0)

    QSETUP(0, m2x0, m2y0, m2z0); QSETUP(1, m2x1, m2y1, m2z1);
    QSETUP(2, m2x2, m2y2, m2z2); QSETUP(3, m2x3, m2y3, m2z3);
    QSETUP(4, m2x4, m2y4, m2z4); QSETUP(5, m2x5, m2y5, m2z5);
    QSETUP(6, m2x6, m2y6, m2z6); QSETUP(7, m2x7, m2y7, m2z7);
#undef QSETUP

    __syncthreads();

    float bb0 = INFINITY, bb1 = INFINITY, bb2 = INFINITY, bb3 = INFINITY;
    float bb4 = INFINITY, bb5 = INFINITY, bb6 = INFINITY, bb7 = INFINITY;
    int cc0 = 0, cc1 = 0, cc2 = 0, cc3 = 0, cc4 = 0, cc5 = 0, cc6 = 0, cc7 = 0;

    for (int c = 0; c < NCHUNK; ++c) {
        float a0 = INFINITY, a1 = INFINITY, a2 = INFINITY, a3 = INFINITY;
        float a4 = INFINITY, a5 = INFINITY, a6 = INFINITY, a7 = INFINITY;

        #pragma unroll
        for (int u = 0; u < CH; u += 2) {
            const float4 t0 = TS[c][u];
            const float4 t1 = TS[c][u + 1];
#define EVAL2(MX, MY, MZ, A) do {                                         \
            const float d0 = CHAIN(t0, MX, MY, MZ);                       \
            const float d1 = CHAIN(t1, MX, MY, MZ);                       \
            A = min3f(d0, d1, A);                                         \
        } while (0)
            EVAL2(m2x0, m2y0, m2z0, a0);
            EVAL2(m2x1, m2y1, m2z1, a1);
            EVAL2(m2x2, m2y2, m2z2, a2);
            EVAL2(m2x3, m2y3, m2z3, a3);
            EVAL2(m2x4, m2y4, m2z4, a4);
            EVAL2(m2x5, m2y5, m2z5, a5);
            EVAL2(m2x6, m2y6, m2z6, a6);
            EVAL2(m2x7, m2y7, m2z7, a7);
#undef EVAL2
        }

#define CUPD(A, BV, CV) do {                                              \
        const bool c_ = (A) < (BV);                                       \
        BV = c_ ? (A) : (BV);                                             \
        CV = c_ ? c : (CV);                                               \
    } while (0)
        CUPD(a0, bb0, cc0); CUPD(a1, bb1, cc1);
        CUPD(a2, bb2, cc2); CUPD(a3, bb3, cc3);
        CUPD(a4, bb4, cc4); CUPD(a5, bb5, cc5);
        CUPD(a6, bb6, cc6); CUPD(a7, bb7, cc7);
#undef CUPD
    }

    const size_t qbase = (((size_t)mod * BB + b) * NN);

    // rescan winning chunk (backward overwrite -> first match), pack, combine
#define FINQ(K, MX, MY, MZ, BV, CV) do {                                  \
        int im = 0;                                                       \
        for (int u = CH - 1; u >= 0; --u) {                               \
            const float4 t = TS[CV][u];                                   \
            const float d = CHAIN(t, MX, MY, MZ);                         \
            im = (d == (BV)) ? ((CV) * CH + u) : im;                      \
        }                                                                 \
        const float q2 = 0.25f * fmaf(MX, MX, fmaf(MY, MY, (MZ) * (MZ)));\
        const float f = (BV) + q2 + 8.0f;                                 \
        const unsigned long long key =                                    \
            ((unsigned long long)__float_as_uint(f) << 32) |              \
            (unsigned int)(mbase + im);                                   \
        atomicMin(&keys[qbase + (size_t)(nb + (K) * TPB)], key);          \
    } while (0)

    FINQ(0, m2x0, m2y0, m2z0, bb0, cc0);
    FINQ(1, m2x1, m2y1, m2z1, bb1, cc1);
    FINQ(2, m2x2, m2y2, m2z2, bb2, cc2);
    FINQ(3, m2x3, m2y3, m2z3, bb3, cc3);
    FINQ(4, m2x4, m2y4, m2z4, bb4, cc4);
    FINQ(5, m2x5, m2y5, m2z5, bb5, cc5);
    FINQ(6, m2x6, m2y6, m2z6, bb6, cc6);
    FINQ(7, m2x7, m2y7, m2z7, bb7, cc7);
#undef FINQ
}

// ---------------- pass 2: unpack winner, compute loss terms -----------------
__global__ __launch_bounds__(TPB) void nn_loss_pass2(
    const float* __restrict__ noisy, const float* __restrict__ clean,
    const float* __restrict__ seeds, const float* __restrict__ stds,
    const float* __restrict__ disp,  const float* __restrict__ noise,
    const unsigned long long* __restrict__ keys,
    float* __restrict__ partials)
{
    __shared__ float red[TPB / 64];
    const int tid = threadIdx.x;
    const int b   = blockIdx.y;
    const int mod = blockIdx.z;
    const int n   = blockIdx.x * TPB + tid;

    const float sx = seeds[b * 3 + 0];
    const float sy = seeds[b * 3 + 1];
    const float sz = seeds[b * 3 + 2];
    float nstd = 0.0f;
    if (mod == 0) nstd = stds[b] * 0.25f;
    else if (mod == 1) nstd = stds[b] * 0.0625f;

    float qx = noisy[((size_t)b * NN + n) * 3 + 0] - sx;
    float qy = noisy[((size_t)b * NN + n) * 3 + 1] - sy;
    float qz = noisy[((size_t)b * NN + n) * 3 + 2] - sz;
    for (int j = 0; j < mod; ++j) {
        const size_t o = (((size_t)j * BB + b) * NN + n) * 3;
        qx += disp[o + 0]; qy += disp[o + 1]; qz += disp[o + 2];
    }
    const size_t od = (((size_t)mod * BB + b) * NN + n) * 3;
    const float dxp = disp[od + 0];
    const float dyp = disp[od + 1];
    const float dzp = disp[od + 2];

    const unsigned gidx =
        (unsigned)(keys[(((size_t)mod * BB + b) * NN) + n] & 0xFFFFFFFFull);

    const size_t oc = ((size_t)b * MM + gidx) * 3;
    float tx = clean[oc + 0] - sx;
    float ty = clean[oc + 1] - sy;
    float tz = clean[oc + 2] - sz;
    if (mod < 2) {
        const size_t on = (((size_t)mod * BB + b) * MM + gidx) * 3;
        tx = fmaf(noise[on + 0], nstd, tx);
        ty = fmaf(noise[on + 1], nstd, ty);
        tz = fmaf(noise[on + 2], nstd, tz);
    }
    const float ex = dxp - (tx - qx);
    const float ey = dyp - (ty - qy);
    const float ez = dzp - (tz - qz);
    float v = fmaf(ex, ex, fmaf(ey, ey, ez * ez));

    for (int o = 32; o; o >>= 1) v += __shfl_down(v, o);
    if ((tid & 63) == 0) red[tid >> 6] = v;
    __syncthreads();
    if (tid == 0) {
        const float s = red[0] + red[1] + red[2] + red[3];
        partials[(((size_t)mod * BB + b) * NXBLK2) + blockIdx.x] = s;
    }
}

__global__ void finalize_kernel(const float* __restrict__ partials, float* __restrict__ out) {
    float s = 0.0f;
    for (int k = threadIdx.x; k < NPART; k += 64) s += partials[k];
    for (int o = 32; o; o >>= 1) s += __shfl_down(s, o);
    if (threadIdx.x == 0) {
        out[0] = s * (1.0f / BB);
        out[1] = s * (1.0f / BB);
    }
}

// ---------------- monolithic fallback (needs only 2 KiB ws) -----------------
#define TM 768
__global__ __launch_bounds__(TPB) void nn_loss_kernel(
    const float* __restrict__ noisy, const float* __restrict__ clean,
    const float* __restrict__ seeds, const float* __restrict__ stds,
    const float* __restrict__ disp,  const float* __restrict__ noise,
    float* __restrict__ partials)
{
    __shared__ float4 tgt[TM];
    __shared__ float red[TPB / 64];
    const int tid = threadIdx.x;
    const int b = blockIdx.y, mod = blockIdx.z;
    const int n = blockIdx.x * TPB + tid;
    const float sx = seeds[b*3+0], sy = seeds[b*3+1], sz = seeds[b*3+2];
    float qx = noisy[((size_t)b*NN+n)*3+0] - sx;
    float qy = noisy[((size_t)b*NN+n)*3+1] - sy;
    float qz = noisy[((size_t)b*NN+n)*3+2] - sz;
    for (int j = 0; j < mod; ++j) {
        const size_t o = (((size_t)j*BB + b)*NN + n)*3;
        qx += disp[o+0]; qy += disp[o+1]; qz += disp[o+2];
    }
    const size_t od = (((size_t)mod*BB + b)*NN + n)*3;
    const float dxp = disp[od+0], dyp = disp[od+1], dzp = disp[od+2];
    float nstd = 0.0f;
    if (mod == 0) nstd = stds[b]*0.25f; else if (mod == 1) nstd = stds[b]*0.0625f;
    const bool nt = (mod < 2);
    const float m2x = -2.0f*qx, m2y = -2.0f*qy, m2z = -2.0f*qz;
    float best = INFINITY; int bestm = 0;
    for (int mt = 0; mt < MM; mt += TM) {
        __syncthreads();
        for (int k = tid; k < TM; k += TPB) {
            const int m = mt + k;
            const size_t oc = ((size_t)b*MM + m)*3;
            float tx = clean[oc+0]-sx, ty = clean[oc+1]-sy, tz = clean[oc+2]-sz;
            if (nt) {
                const size_t on = (((size_t)mod*BB + b)*MM + m)*3;
                tx = fmaf(noise[on+0], nstd, tx);
                ty = fmaf(noise[on+1], nstd, ty);
                tz = fmaf(noise[on+2], nstd, tz);
            }
            tgt[k] = make_float4(tx, ty, tz, fmaf(tx,tx,fmaf(ty,ty,tz*tz)));
        }
        __syncthreads();
        #pragma unroll 8
        for (int k = 0; k < TM; ++k) {
            const float4 t = tgt[k];
            const float d2 = fmaf(m2x, t.x, fmaf(m2y, t.y, fmaf(m2z, t.z, t.w)));
            if (d2 < best) { best = d2; bestm = mt + k; }
        }
    }
    const size_t oc = ((size_t)b*MM + bestm)*3;
    float tx = clean[oc+0]-sx, ty = clean[oc+1]-sy, tz = clean[oc+2]-sz;
    if (nt) {
        const size_t on = (((size_t)mod*BB + b)*MM + bestm)*3;
        tx = fmaf(noise[on+0], nstd, tx);
        ty = fmaf(noise[on+1], nstd, ty);
        tz = fmaf(noise[on+2], nstd, tz);
    }
    const float ex = dxp - (tx - qx), ey = dyp - (ty - qy), ez = dzp - (tz - qz);
    float v = fmaf(ex, ex, fmaf(ey, ey, ez*ez));
    for (int o = 32; o; o >>= 1) v += __shfl_down(v, o);
    if ((tid & 63) == 0) red[tid >> 6] = v;
    __syncthreads();
    if (tid == 0)
        partials[(((size_t)mod*BB + b)*NXBLK2) + blockIdx.x] = red[0]+red[1]+red[2]+red[3];
}

extern "C" void kernel_launch(void* const* d_in, const int* in_sizes, int n_in,
                              void* d_out, int out_size, void* d_ws, size_t ws_size,
                              hipStream_t stream) {
    const float* noisy = (const float*)d_in[0];
    const float* clean = (const float*)d_in[1];
    const float* seeds = (const float*)d_in[2];
    const float* stds  = (const float*)d_in[3];
    const float* disp  = (const float*)d_in[4];
    const float* noise = (const float*)d_in[5];
    float* out = (float*)d_out;

    if (ws_size >= WS_NEED) {
        unsigned long long* keys = (unsigned long long*)d_ws;
        float* partials = (float*)((char*)d_ws + KEYB);
        hipMemsetAsync(d_ws, 0xFF, KEYB, stream);
        dim3 g1(NXB, BB, NMOD * SLICES);
        nn_min_kernel<<<g1, TPB, 0, stream>>>(noisy, clean, seeds, stds, disp, noise, keys);
        dim3 g2(NXBLK2, BB, NMOD);
        nn_loss_pass2<<<g2, TPB, 0, stream>>>(noisy, clean, seeds, stds, disp, noise, keys, partials);
        finalize_kernel<<<1, 64, 0, stream>>>(partials, out);
    } else {
        float* partials = (float*)d_ws;
        dim3 grid(NXBLK2, BB, NMOD);
        nn_loss_kernel<<<grid, TPB, 0, stream>>>(noisy, clean, seeds, stds, disp, noise, partials);
        finalize_kernel<<<1, 64, 0, stream>>>(partials, out);
    }
}

// Round 8
// 76.263 us; speedup vs baseline: 1.2946x; 1.1006x over previous
//
#include <hip/hip_runtime.h>
#include <math.h>

#define NMOD 4
#define BB   8
#define NN   4096
#define MM   4608
#define TPB  256

// ---- fast path geometry ----
#define QPT      4                      // queries per thread (named scalars)
#define QPB      (TPB * QPT)            // 1024 queries per block
#define NXB      (NN / QPB)             // 4
#define SLICES   16
#define SLICE_M  (MM / SLICES)          // 288
#define CH       16                     // chunk size for argmin bookkeeping
#define NCHUNK   (SLICE_M / CH)         // 18
#define CHP      (CH + 1)               // padded chunk stride (breaks bank aliasing)
#define QCOUNT   (NMOD * BB * NN)       // 131072
#define KEYB     ((size_t)SLICES * QCOUNT * 8)   // 16.78 MB per-slice keys
#define NXBLK2   (NN / TPB)             // 16
#define NPART    (NMOD * BB * NXBLK2)   // 512
#define WS_NEED  (KEYB + NPART * sizeof(float))

static __device__ __forceinline__ float min3f(float a, float b, float c) {
    float d;
    asm("v_min3_f32 %0, %1, %2, %3" : "=v"(d) : "v"(a), "v"(b), "v"(c));
    return d;
}

// identical FMA chain used in scan and rescan -> bit-exact equality
#define CHAIN(T, MX, MY, MZ) \
    fmaf(MX, (T).x, fmaf(MY, (T).y, fmaf(MZ, (T).z, (T).w)))

// ---------------- pass 1: chunked min3 slice argmin, no atomics -------------
__global__ __launch_bounds__(TPB, 8) void nn_min_kernel(
    const float* __restrict__ noisy, const float* __restrict__ clean,
    const float* __restrict__ seeds, const float* __restrict__ stds,
    const float* __restrict__ disp,  const float* __restrict__ noise,
    unsigned long long* __restrict__ keys)
{
    __shared__ float4 TS[NCHUNK][CHP];   // {x,y,z,||t||^2}, +1 pad per chunk

    const int tid   = threadIdx.x;
    const int b     = blockIdx.y;
    const int mod   = blockIdx.z >> 4;
    const int sl    = blockIdx.z & 15;
    const int mbase = sl * SLICE_M;
    const int nb    = blockIdx.x * QPB + tid;

    const float sx = seeds[b * 3 + 0];
    const float sy = seeds[b * 3 + 1];
    const float sz = seeds[b * 3 + 2];
    float nstd = 0.0f;
    if (mod == 0) nstd = stds[b] * 0.25f;
    else if (mod == 1) nstd = stds[b] * 0.0625f;
    const bool nt = (mod < 2);

    // stage this 288-target slice
    for (int k = tid; k < SLICE_M; k += TPB) {
        const int m = mbase + k;
        const size_t oc = ((size_t)b * MM + m) * 3;
        float tx = clean[oc + 0] - sx;
        float ty = clean[oc + 1] - sy;
        float tz = clean[oc + 2] - sz;
        if (nt) {
            const size_t on = (((size_t)mod * BB + b) * MM + m) * 3;
            tx = fmaf(noise[on + 0], nstd, tx);
            ty = fmaf(noise[on + 1], nstd, ty);
            tz = fmaf(noise[on + 2], nstd, tz);
        }
        const float tw = fmaf(tx, tx, fmaf(ty, ty, tz * tz));
        TS[k >> 4][k & 15] = make_float4(tx, ty, tz, tw);
    }

    // ---- 4 queries, all named scalars (no arrays -> no scratch) ----
    float m2x0, m2y0, m2z0, m2x1, m2y1, m2z1;
    float m2x2, m2y2, m2z2, m2x3, m2y3, m2z3;

#define QSETUP(K, MX, MY, MZ) do {                                        \
        const int n = nb + (K) * TPB;                                     \
        const size_t o0 = ((size_t)b * NN + n) * 3;                       \
        float qx = noisy[o0 + 0] - sx;                                    \
        float qy = noisy[o0 + 1] - sy;                                    \
        float qz = noisy[o0 + 2] - sz;                                    \
        for (int j = 0; j < mod; ++j) {                                   \
            const size_t o = (((size_t)j * BB + b) * NN + n) * 3;         \
            qx += disp[o + 0]; qy += disp[o + 1]; qz += disp[o + 2];      \
        }                                                                 \
        MX = -2.0f * qx; MY = -2.0f * qy; MZ = -2.0f * qz;                \
    } while (0)

    QSETUP(0, m2x0, m2y0, m2z0); QSETUP(1, m2x1, m2y1, m2z1);
    QSETUP(2, m2x2, m2y2, m2z2); QSETUP(3, m2x3, m2y3, m2z3);
#undef QSETUP

    __syncthreads();

    float bb0 = INFINITY, bb1 = INFINITY, bb2 = INFINITY, bb3 = INFINITY;
    int cc0 = 0, cc1 = 0, cc2 = 0, cc3 = 0;

    for (int c = 0; c < NCHUNK; ++c) {
        float a0 = INFINITY, a1 = INFINITY, a2 = INFINITY, a3 = INFINITY;

        #pragma unroll
        for (int u = 0; u < CH; u += 2) {
            const float4 t0 = TS[c][u];
            const float4 t1 = TS[c][u + 1];
#define EVAL2(MX, MY, MZ, A) do {                                         \
            const float d0 = CHAIN(t0, MX, MY, MZ);                       \
            const float d1 = CHAIN(t1, MX, MY, MZ);                       \
            A = min3f(d0, d1, A);                                         \
        } while (0)
            EVAL2(m2x0, m2y0, m2z0, a0);
            EVAL2(m2x1, m2y1, m2z1, a1);
            EVAL2(m2x2, m2y2, m2z2, a2);
            EVAL2(m2x3, m2y3, m2z3, a3);
#undef EVAL2
        }

#define CUPD(A, BV, CV) do {                                              \
        const bool c_ = (A) < (BV);                                       \
        BV = c_ ? (A) : (BV);                                             \
        CV = c_ ? c : (CV);                                               \
    } while (0)
        CUPD(a0, bb0, cc0); CUPD(a1, bb1, cc1);
        CUPD(a2, bb2, cc2); CUPD(a3, bb3, cc3);
#undef CUPD
    }

    unsigned long long* __restrict__ kslice = keys + (size_t)sl * QCOUNT
                                            + (((size_t)mod * BB + b) * NN);

    // rescan winning chunk (backward overwrite -> first match), pack, store
#define FINQ(K, MX, MY, MZ, BV, CV) do {                                  \
        int im = 0;                                                       \
        for (int u = CH - 1; u >= 0; --u) {                               \
            const float4 t = TS[CV][u];                                   \
            const float d = CHAIN(t, MX, MY, MZ);                         \
            im = (d == (BV)) ? ((CV) * CH + u) : im;                      \
        }                                                                 \
        const float q2 = 0.25f * fmaf(MX, MX, fmaf(MY, MY, (MZ) * (MZ)));\
        const float f = (BV) + q2 + 8.0f;                                 \
        const unsigned long long key =                                    \
            ((unsigned long long)__float_as_uint(f) << 32) |              \
            (unsigned int)(mbase + im);                                   \
        kslice[nb + (K) * TPB] = key;                                     \
    } while (0)

    FINQ(0, m2x0, m2y0, m2z0, bb0, cc0);
    FINQ(1, m2x1, m2y1, m2z1, bb1, cc1);
    FINQ(2, m2x2, m2y2, m2z2, bb2, cc2);
    FINQ(3, m2x3, m2y3, m2z3, bb3, cc3);
#undef FINQ
}

// ---------------- pass 2: combine slices, unpack winner, loss ---------------
__global__ __launch_bounds__(TPB) void nn_loss_pass2(
    const float* __restrict__ noisy, const float* __restrict__ clean,
    const float* __restrict__ seeds, const float* __restrict__ stds,
    const float* __restrict__ disp,  const float* __restrict__ noise,
    const unsigned long long* __restrict__ keys,
    float* __restrict__ partials)
{
    __shared__ float red[TPB / 64];
    const int tid = threadIdx.x;
    const int b   = blockIdx.y;
    const int mod = blockIdx.z;
    const int n   = blockIdx.x * TPB + tid;

    const float sx = seeds[b * 3 + 0];
    const float sy = seeds[b * 3 + 1];
    const float sz = seeds[b * 3 + 2];
    float nstd = 0.0f;
    if (mod == 0) nstd = stds[b] * 0.25f;
    else if (mod == 1) nstd = stds[b] * 0.0625f;

    float qx = noisy[((size_t)b * NN + n) * 3 + 0] - sx;
    float qy = noisy[((size_t)b * NN + n) * 3 + 1] - sy;
    float qz = noisy[((size_t)b * NN + n) * 3 + 2] - sz;
    for (int j = 0; j < mod; ++j) {
        const size_t o = (((size_t)j * BB + b) * NN + n) * 3;
        qx += disp[o + 0]; qy += disp[o + 1]; qz += disp[o + 2];
    }
    const size_t od = (((size_t)mod * BB + b) * NN + n) * 3;
    const float dxp = disp[od + 0];
    const float dyp = disp[od + 1];
    const float dzp = disp[od + 2];

    const size_t q = (((size_t)mod * BB + b) * NN) + n;
    unsigned long long k = keys[q];
    #pragma unroll
    for (int s = 1; s < SLICES; ++s) {
        const unsigned long long v = keys[(size_t)s * QCOUNT + q];
        k = v < k ? v : k;
    }
    const unsigned gidx = (unsigned)(k & 0xFFFFFFFFull);

    const size_t oc = ((size_t)b * MM + gidx) * 3;
    float tx = clean[oc + 0] - sx;
    float ty = clean[oc + 1] - sy;
    float tz = clean[oc + 2] - sz;
    if (mod < 2) {
        const size_t on = (((size_t)mod * BB + b) * MM + gidx) * 3;
        tx = fmaf(noise[on + 0], nstd, tx);
        ty = fmaf(noise[on + 1], nstd, ty);
        tz = fmaf(noise[on + 2], nstd, tz);
    }
    const float ex = dxp - (tx - qx);
    const float ey = dyp - (ty - qy);
    const float ez = dzp - (tz - qz);
    float v = fmaf(ex, ex, fmaf(ey, ey, ez * ez));

    for (int o = 32; o; o >>= 1) v += __shfl_down(v, o);
    if ((tid & 63) == 0) red[tid >> 6] = v;
    __syncthreads();
    if (tid == 0) {
        const float s = red[0] + red[1] + red[2] + red[3];
        partials[(((size_t)mod * BB + b) * NXBLK2) + blockIdx.x] = s;
    }
}

__global__ void finalize_kernel(const float* __restrict__ partials, float* __restrict__ out) {
    float s = 0.0f;
    for (int k = threadIdx.x; k < NPART; k += 64) s += partials[k];
    for (int o = 32; o; o >>= 1) s += __shfl_down(s, o);
    if (threadIdx.x == 0) {
        out[0] = s * (1.0f / BB);
        out[1] = s * (1.0f / BB);
    }
}

// ---------------- monolithic fallback (needs only 2 KiB ws) -----------------
#define TM 768
__global__ __launch_bounds__(TPB) void nn_loss_kernel(
    const float* __restrict__ noisy, const float* __restrict__ clean,
    const float* __restrict__ seeds, const float* __restrict__ stds,
    const float* __restrict__ disp,  const float* __restrict__ noise,
    float* __restrict__ partials)
{
    __shared__ float4 tgt[TM];
    __shared__ float red[TPB / 64];
    const int tid = threadIdx.x;
    const int b = blockIdx.y, mod = blockIdx.z;
    const int n = blockIdx.x * TPB + tid;
    const float sx = seeds[b*3+0], sy = seeds[b*3+1], sz = seeds[b*3+2];
    float qx = noisy[((size_t)b*NN+n)*3+0] - sx;
    float qy = noisy[((size_t)b*NN+n)*3+1] - sy;
    float qz = noisy[((size_t)b*NN+n)*3+2] - sz;
    for (int j = 0; j < mod; ++j) {
        const size_t o = (((size_t)j*BB + b)*NN + n)*3;
        qx += disp[o+0]; qy += disp[o+1]; qz += disp[o+2];
    }
    const size_t od = (((size_t)mod*BB + b)*NN + n)*3;
    const float dxp = disp[od+0], dyp = disp[od+1], dzp = disp[od+2];
    float nstd = 0.0f;
    if (mod == 0) nstd = stds[b]*0.25f; else if (mod == 1) nstd = stds[b]*0.0625f;
    const bool nt = (mod < 2);
    const float m2x = -2.0f*qx, m2y = -2.0f*qy, m2z = -2.0f*qz;
    float best = INFINITY; int bestm = 0;
    for (int mt = 0; mt < MM; mt += TM) {
        __syncthreads();
        for (int k = tid; k < TM; k += TPB) {
            const int m = mt + k;
            const size_t oc = ((size_t)b*MM + m)*3;
            float tx = clean[oc+0]-sx, ty = clean[oc+1]-sy, tz = clean[oc+2]-sz;
            if (nt) {
                const size_t on = (((size_t)mod*BB + b)*MM + m)*3;
                tx = fmaf(noise[on+0], nstd, tx);
                ty = fmaf(noise[on+1], nstd, ty);
                tz = fmaf(noise[on+2], nstd, tz);
            }
            tgt[k] = make_float4(tx, ty, tz, fmaf(tx,tx,fmaf(ty,ty,tz*tz)));
        }
        __syncthreads();
        #pragma unroll 8
        for (int k = 0; k < TM; ++k) {
            const float4 t = tgt[k];
            const float d2 = fmaf(m2x, t.x, fmaf(m2y, t.y, fmaf(m2z, t.z, t.w)));
            if (d2 < best) { best = d2; bestm = mt + k; }
        }
    }
    const size_t oc = ((size_t)b*MM + bestm)*3;
    float tx = clean[oc+0]-sx, ty = clean[oc+1]-sy, tz = clean[oc+2]-sz;
    if (nt) {
        const size_t on = (((size_t)mod*BB + b)*MM + bestm)*3;
        tx = fmaf(noise[on+0], nstd, tx);
        ty = fmaf(noise[on+1], nstd, ty);
        tz = fmaf(noise[on+2], nstd, tz);
    }
    const float ex = dxp - (tx - qx), ey = dyp - (ty - qy), ez = dzp - (tz - qz);
    float v = fmaf(ex, ex, fmaf(ey, ey, ez*ez));
    for (int o = 32; o; o >>= 1) v += __shfl_down(v, o);
    if ((tid & 63) == 0) red[tid >> 6] = v;
    __syncthreads();
    if (tid == 0)
        partials[(((size_t)mod*BB + b)*NXBLK2) + blockIdx.x] = red[0]+red[1]+red[2]+red[3];
}

extern "C" void kernel_launch(void* const* d_in, const int* in_sizes, int n_in,
                              void* d_out, int out_size, void* d_ws, size_t ws_size,
                              hipStream_t stream) {
    const float* noisy = (const float*)d_in[0];
    const float* clean = (const float*)d_in[1];
    const float* seeds = (const float*)d_in[2];
    const float* stds  = (const float*)d_in[3];
    const float* disp  = (const float*)d_in[4];
    const float* noise = (const float*)d_in[5];
    float* out = (float*)d_out;

    if (ws_size >= WS_NEED) {
        unsigned long long* keys = (unsigned long long*)d_ws;
        float* partials = (float*)((char*)d_ws + KEYB);
        dim3 g1(NXB, BB, NMOD * SLICES);
        nn_min_kernel<<<g1, TPB, 0, stream>>>(noisy, clean, seeds, stds, disp, noise, keys);
        dim3 g2(NXBLK2, BB, NMOD);
        nn_loss_pass2<<<g2, TPB, 0, stream>>>(noisy, clean, seeds, stds, disp, noise, keys, partials);
        finalize_kernel<<<1, 64, 0, stream>>>(partials, out);
    } else {
        float* partials = (float*)d_ws;
        dim3 grid(NXBLK2, BB, NMOD);
        nn_loss_kernel<<<grid, TPB, 0, stream>>>(noisy, clean, seeds, stds, disp, noise, partials);
        finalize_kernel<<<1, 64, 0, stream>>>(partials, out);
    }
}